// Round 10
// baseline (106.880 us; speedup 1.0000x reference)
//
#include <hip/hip_runtime.h>

typedef __bf16 bf16_t;
typedef __bf16 bf16x8 __attribute__((ext_vector_type(8)));
typedef __bf16 bf16x4 __attribute__((ext_vector_type(4)));
typedef short  s16x4  __attribute__((ext_vector_type(4)));
typedef float  f32x4  __attribute__((ext_vector_type(4)));
typedef unsigned int u32;

#define BB 2
#define SS 2048
#define EE 768
#define HH 12
#define DD 64
#define NROW (BB*SS)   // 4096

// async global->LDS, 16B per lane. LDS dest = firstlane(base)+lane*16 (linear).
#define GLDS16(gp, lp) __builtin_amdgcn_global_load_lds( \
    (const __attribute__((address_space(1))) u32*)(gp),   \
    (__attribute__((address_space(3))) u32*)(lp), 16, 0, 0)

#if __has_builtin(__builtin_amdgcn_mfma_f32_16x16x16bf16_1k)
#define MFMA16_BUILTIN 1
static __device__ __forceinline__ f32x4 mfma_16x16x16_bf16(bf16x4 a, bf16x4 b, f32x4 c) {
  return __builtin_amdgcn_mfma_f32_16x16x16bf16_1k(
      __builtin_bit_cast(s16x4, a), __builtin_bit_cast(s16x4, b), c, 0, 0, 0);
}
#else
#define MFMA16_BUILTIN 0
static __device__ __forceinline__ f32x4 mfma_16x16x16_bf16(bf16x4 a, bf16x4 b, f32x4 c) {
  asm volatile("v_mfma_f32_16x16x16_bf16 %0, %1, %2, %0" : "+v"(c) : "v"(a), "v"(b));
  return c;
}
#endif

// ---------------- pack weights: wt[z][n][k] = w_z[k][n] (bf16) ----------------
__global__ __launch_bounds__(256) void pack_w_kernel(
    const float* __restrict__ wq, const float* __restrict__ wk,
    const float* __restrict__ wv, const float* __restrict__ wo,
    bf16_t* __restrict__ wt)
{
  __shared__ float tile[64][65];
  const float* src = (blockIdx.z==0)?wq:(blockIdx.z==1)?wk:(blockIdx.z==2)?wv:wo;
  const int k0 = blockIdx.x*64, n0 = blockIdx.y*64;
  const int t = threadIdx.x;
  #pragma unroll
  for (int it=0; it<16; ++it) {
    int idx = it*256+t, r = idx>>6, c = idx&63;
    tile[r][c] = src[(size_t)(k0+r)*EE + n0 + c];
  }
  __syncthreads();
  bf16_t* dst = wt + (size_t)blockIdx.z*EE*EE;
  #pragma unroll
  for (int it=0; it<16; ++it) {
    int idx = it*256+t, r = idx>>6, c = idx&63;
    dst[(size_t)(n0+r)*EE + k0 + c] = (bf16_t)tile[c][r];
  }
}

// ---------------- LayerNorm (fp32 in, bf16 out) ----------------
__global__ __launch_bounds__(256) void ln_kernel(
    const float* __restrict__ x, const float* __restrict__ w,
    const float* __restrict__ bvec, bf16_t* __restrict__ xn)
{
  const int row = blockIdx.x, t = threadIdx.x;
  const float* xr = x + (size_t)row*EE;
  float v0 = xr[t], v1 = xr[t+256], v2 = xr[t+512];
  float s  = v0+v1+v2;
  float ss = v0*v0 + v1*v1 + v2*v2;
  #pragma unroll
  for (int m=1; m<64; m<<=1) { s += __shfl_xor(s,m); ss += __shfl_xor(ss,m); }
  __shared__ float red[2][4];
  const int wid = t>>6, lane = t&63;
  if (lane==0) { red[0][wid]=s; red[1][wid]=ss; }
  __syncthreads();
  s  = red[0][0]+red[0][1]+red[0][2]+red[0][3];
  ss = red[1][0]+red[1][1]+red[1][2]+red[1][3];
  const float mu   = s*(1.0f/EE);
  const float rstd = rsqrtf(ss*(1.0f/EE) - mu*mu + 1e-5f);
  bf16_t* xo = xn + (size_t)row*EE;
  xo[t      ] = (bf16_t)((v0-mu)*rstd*w[t      ] + bvec[t      ]);
  xo[t + 256] = (bf16_t)((v1-mu)*rstd*w[t + 256] + bvec[t + 256]);
  xo[t + 512] = (bf16_t)((v2-mu)*rstd*w[t + 512] + bvec[t + 512]);
}

// ---------------- QKV GEMM: 2-buf prefetch (measured-best, R4 bench) ----------------
__global__ __launch_bounds__(256) void gemm_qkv_kernel(
    const bf16_t* __restrict__ xn, const bf16_t* __restrict__ wt,
    const float* __restrict__ bq, const float* __restrict__ bk, const float* __restrict__ bv,
    bf16_t* __restrict__ qb, bf16_t* __restrict__ kb, bf16_t* __restrict__ vb)
{
  __shared__ __align__(16) bf16_t As[2][128][32];
  __shared__ __align__(16) bf16_t Bs[2][128][32];
  const int bm = blockIdx.x, by = blockIdx.y;
  const int mat = by/6, nb = by%6;
  const bf16_t* W = wt + (size_t)mat*EE*EE + (size_t)nb*128*EE;
  const float* bias = (mat==0)?bq:(mat==1)?bk:bv;
  bf16_t* outp = (mat==0)?qb:(mat==1)?kb:vb;
  const int t = threadIdx.x, lane = t&63, wid = t>>6;
  const int wr = wid>>1, wc = wid&1;
  const int lrow = lane&15, lk = lane>>4;
  const bf16_t* Ag = xn + (size_t)bm*128*EE;

  const int srow = t>>2, sp = t&3;
  const int sg = sp ^ ((srow>>1)&3);
  const int pcs = (lrow>>1)&3;

  auto stage = [&](int buf, int k0) {
    const bf16_t* asrc = Ag + (size_t)srow*EE + k0 + sg*8;
    const bf16_t* bsrc = W  + (size_t)srow*EE + k0 + sg*8;
    GLDS16(asrc,                 &As[buf][0][0] + t*8);
    GLDS16(asrc + (size_t)64*EE, &As[buf][0][0] + 2048 + t*8);
    GLDS16(bsrc,                 &Bs[buf][0][0] + t*8);
    GLDS16(bsrc + (size_t)64*EE, &Bs[buf][0][0] + 2048 + t*8);
  };

  f32x4 acc[4][4];
  #pragma unroll
  for (int i=0;i<4;++i)
    #pragma unroll
    for (int j=0;j<4;++j) acc[i][j] = (f32x4){0.f,0.f,0.f,0.f};

  stage(0, 0);
  __syncthreads();
  int cur = 0;
  for (int k0=0; k0<EE; k0+=32) {
    if (k0+32 < EE) stage(cur^1, k0+32);   // prefetch flies under compute
    bf16x8 af[4], bfv[4];
    #pragma unroll
    for (int mi=0;mi<4;++mi) af[mi]  = *(const bf16x8*)&As[cur][wr*64+mi*16+lrow][(lk^pcs)*8];
    #pragma unroll
    for (int ni=0;ni<4;++ni) bfv[ni] = *(const bf16x8*)&Bs[cur][wc*64+ni*16+lrow][(lk^pcs)*8];
    #pragma unroll
    for (int mi=0;mi<4;++mi)
      #pragma unroll
      for (int ni=0;ni<4;++ni)
        acc[mi][ni] = __builtin_amdgcn_mfma_f32_16x16x32_bf16(af[mi], bfv[ni], acc[mi][ni], 0,0,0);
    __syncthreads();   // drains prefetch + guards buffer reuse
    cur ^= 1;
  }
  const int m_base = bm*128 + wr*64;
  const int n_base = nb*128 + wc*64;
  #pragma unroll
  for (int ni=0;ni<4;++ni) {
    const int col = n_base + ni*16 + lrow;
    const float bias_v = bias[col];
    #pragma unroll
    for (int mi=0;mi<4;++mi) {
      #pragma unroll
      for (int r=0;r<4;++r) {
        int row = m_base + mi*16 + 4*lk + r;
        outp[(size_t)row*EE + col] = (bf16_t)(acc[mi][ni][r] + bias_v);
      }
    }
  }
}

// ---------------- V transpose: v[b,s,h,d] -> vt[(b*H+h)*D + d][s] ----------------
__global__ __launch_bounds__(256) void vtrans_kernel(
    const bf16_t* __restrict__ v, bf16_t* __restrict__ vt)
{
  __shared__ __align__(16) bf16_t tile[64][72];
  const int j0 = blockIdx.x*64, bh = blockIdx.y;
  const int b = bh/HH, h = bh%HH;
  const int t = threadIdx.x;
  #pragma unroll
  for (int it=0; it<2; ++it) {
    int idx = it*256+t, r = idx>>3, c8 = (idx&7)*8;
    *(bf16x8*)&tile[r][c8] = *(const bf16x8*)(v + (size_t)(b*SS + j0 + r)*EE + h*DD + c8);
  }
  __syncthreads();
  #pragma unroll
  for (int it=0; it<2; ++it) {
    int idx = it*256+t, d = idx>>3, c8 = (idx&7)*8;
    bf16x8 val;
    #pragma unroll
    for (int i=0;i<8;++i) val[i] = tile[c8+i][d];
    *(bf16x8*)(vt + ((size_t)bh*DD + d)*SS + j0 + c8) = val;
  }
}

// ---------------- flash attention (anti-causal: attend j >= i) ----------------
// LDS-traffic-halved structure: 128 threads = 2 waves; each wave computes
// 32 q-rows as TWO 16-row groups that SHARE the kf/vf LDS fragments (each
// fragment read once, used by 2 MFMAs). Per-wave LDS bytes per q-row halve —
// the R9 accounting showed the LDS pipe (~811MB total ds_read) was the
// saturated resource. Snake remap + fixed-max softmax + 2-buf prefetch kept.
__global__ __launch_bounds__(128) void attn_kernel(
    const bf16_t* __restrict__ qb, const bf16_t* __restrict__ kb,
    const bf16_t* __restrict__ vt, bf16_t* __restrict__ hb)
{
  __shared__ __align__(16) bf16_t Ks[2][64][64];   // K tile [j][d]
  __shared__ __align__(16) bf16_t Vts[2][64][64];  // V^T tile [d][j]
  __shared__ __align__(16) bf16_t Os[64][72];      // epilogue transpose

  // snake remap: blocks bid, bid+256, bid+512 share a CU -> complementary work
  const int bid = blockIdx.x;
  const int rnd = bid >> 8, g8 = bid & 255;
  const int item = (rnd == 1) ? (511 - g8) : (rnd*256 + g8);
  const int qt = item / 24, bh = item % 24;

  const int i0 = qt*64, b = bh/HH, h = bh%HH;
  const int t = threadIdx.x, lane = t&63, w = t>>6;   // w = wave id (0/1)
  const int lrow = lane&15, lk = lane>>4;

  const int sr = t>>3, sp = t&7;          // staging row-in-group / phys chunk
  const int sgc = sp ^ (sr&7);            // pre-swizzled global chunk
  const bf16_t* kbase  = kb + (size_t)b*SS*EE + h*DD;
  const bf16_t* vtbase = vt + (size_t)bh*DD*SS;

  // Q fragments (B-operand) for the wave's 2 q-groups
  bf16x8 qf[2][2];
  #pragma unroll
  for (int g=0; g<2; ++g) {
    const bf16_t* qrow = qb + (size_t)(b*SS + i0 + w*32 + g*16 + lrow)*EE + h*DD;
    qf[g][0] = *(const bf16x8*)(qrow + lk*8);
    qf[g][1] = *(const bf16x8*)(qrow + 32 + lk*8);
  }

  f32x4 acc[2][4];
  #pragma unroll
  for (int g=0; g<2; ++g)
    #pragma unroll
    for (int i=0;i<4;++i) acc[g][i] = (f32x4){0.f,0.f,0.f,0.f};
  float lsum[2] = {0.f, 0.f};
  const int kkey = lrow&7;

  auto stage = [&](int buf, int jt) {
    const int j0v = jt*64;
    #pragma unroll
    for (int i=0;i<4;++i)
      GLDS16(kbase + (size_t)(j0v + i*16 + sr)*EE + sgc*8,
             &Ks[buf][0][0] + (i*128 + t)*8);
    #pragma unroll
    for (int i=0;i<4;++i)
      GLDS16(vtbase + (size_t)(i*16 + sr)*SS + j0v + sgc*8,
             &Vts[buf][0][0] + (i*128 + t)*8);
  };

  // p = e^(qk/8 - 24) = 2^(a*0.1803369 - 34.62468); fixed max -> additive
#define ATTN_TILE(CUR, MASKED) do {                                          \
    bf16x4 pb[2][4];                                                         \
    _Pragma("unroll")                                                        \
    for (int sj=0;sj<4;++sj) {                                               \
      const bf16_t* krow = &Ks[CUR][sj*16+lrow][0];                          \
      bf16x8 kf0 = *(const bf16x8*)(krow + ((lk^kkey)<<3));                  \
      bf16x8 kf1 = *(const bf16x8*)(krow + (((lk+4)^kkey)<<3));              \
      _Pragma("unroll")                                                      \
      for (int g=0; g<2; ++g) {                                              \
        f32x4 a = (f32x4){0.f,0.f,0.f,0.f};                                  \
        a = __builtin_amdgcn_mfma_f32_16x16x32_bf16(kf0, qf[g][0], a, 0,0,0);\
        a = __builtin_amdgcn_mfma_f32_16x16x32_bf16(kf1, qf[g][1], a, 0,0,0);\
        const int iloc = w*32 + g*16 + lrow;                                 \
        _Pragma("unroll")                                                    \
        for (int r=0;r<4;++r) {                                              \
          float ee = a[r]*0.180336878f - 34.6246784f;                        \
          if (MASKED && (sj*16 + 4*lk + r) < iloc) ee = -1e30f;              \
          float p = exp2f(ee);                                               \
          lsum[g] += p;                                                      \
          pb[g][sj][r] = (bf16_t)p;                                          \
        }                                                                    \
      }                                                                      \
    }                                                                        \
    _Pragma("unroll")                                                        \
    for (int sd=0;sd<4;++sd) {                                               \
      const bf16_t* vrow = &Vts[CUR][sd*16+lrow][0];                         \
      _Pragma("unroll")                                                      \
      for (int sj=0;sj<4;++sj) {                                             \
        bf16x4 vf = *(const bf16x4*)(vrow + (((2*sj+(lk>>1))^kkey)<<3) + ((lk&1)<<2)); \
        acc[0][sd] = mfma_16x16x16_bf16(vf, pb[0][sj], acc[0][sd]);          \
        acc[1][sd] = mfma_16x16x16_bf16(vf, pb[1][sj], acc[1][sd]);          \
      }                                                                      \
    }                                                                        \
  } while(0)

  const int ntiles = SS/64 - qt;  // 1..32
  stage(0, qt);
  __syncthreads();                 // buf0 ready
  if (ntiles > 1) stage(1, qt+1);  // prefetch flies under diagonal compute
  ATTN_TILE(0, true);              // diagonal tile, masked
#if !MFMA16_BUILTIN
  asm volatile("s_nop 7\n\ts_nop 7");
#endif
  __syncthreads();

  int cur = 1;
  for (int it2=1; it2<ntiles; ++it2) {
    if (it2+1 < ntiles) stage(cur^1, qt+it2+1);
    ATTN_TILE(cur, false);
#if !MFMA16_BUILTIN
    asm volatile("s_nop 7\n\ts_nop 7");
#endif
    __syncthreads();
    cur ^= 1;
  }
#undef ATTN_TILE

  // deferred row-sum reduce (one shuffle pair per group for the whole kernel)
  #pragma unroll
  for (int g=0; g<2; ++g) {
    lsum[g] += __shfl_xor(lsum[g], 16);
    lsum[g] += __shfl_xor(lsum[g], 32);
  }

  // epilogue: transpose O through padded Os for coalesced stores
  #pragma unroll
  for (int g=0; g<2; ++g) {
    const float inv = 1.0f / lsum[g];
    const int erow = w*32 + g*16 + lrow;
    #pragma unroll
    for (int sd=0;sd<4;++sd) {
      bf16x4 ov;
      #pragma unroll
      for (int r=0;r<4;++r) ov[r] = (bf16_t)(acc[g][sd][r] * inv);
      *(bf16x4*)&Os[erow][sd*16 + 4*lk] = ov;
    }
  }
  __syncthreads();
  const int rq = t>>1, half = t&1;
  bf16_t* orow = hb + (size_t)(b*SS + i0 + rq)*EE + h*DD + half*32;
  #pragma unroll
  for (int k=0;k<4;++k)
    *(bf16x8*)(orow + k*8) = *(const bf16x8*)&Os[rq][half*32 + k*8];
}

// ---------------- output GEMM: out[4096,768] f32 = h @ Wo + bo ----------------
__global__ __launch_bounds__(256) void gemm_out_kernel(
    const bf16_t* __restrict__ hbuf, const bf16_t* __restrict__ wto,
    const float* __restrict__ bo, float* __restrict__ out)
{
  __shared__ __align__(16) bf16_t As[2][128][32];
  __shared__ __align__(16) bf16_t Bs[2][128][32];
  const int bm = blockIdx.x, nb = blockIdx.y;
  const bf16_t* W = wto + (size_t)nb*128*EE;
  const int t = threadIdx.x, lane = t&63, wid = t>>6;
  const int wr = wid>>1, wc = wid&1;
  const int lrow = lane&15, lk = lane>>4;
  const bf16_t* Ag = hbuf + (size_t)bm*128*EE;

  const int srow = t>>2, sp = t&3;
  const int sg = sp ^ ((srow>>1)&3);
  const int pcs = (lrow>>1)&3;

  auto stage = [&](int buf, int k0) {
    const bf16_t* asrc = Ag + (size_t)srow*EE + k0 + sg*8;
    const bf16_t* bsrc = W  + (size_t)srow*EE + k0 + sg*8;
    GLDS16(asrc,                 &As[buf][0][0] + t*8);
    GLDS16(asrc + (size_t)64*EE, &As[buf][0][0] + 2048 + t*8);
    GLDS16(bsrc,                 &Bs[buf][0][0] + t*8);
    GLDS16(bsrc + (size_t)64*EE, &Bs[buf][0][0] + 2048 + t*8);
  };

  f32x4 acc[4][4];
  #pragma unroll
  for (int i=0;i<4;++i)
    #pragma unroll
    for (int j=0;j<4;++j) acc[i][j] = (f32x4){0.f,0.f,0.f,0.f};

  stage(0, 0);
  __syncthreads();
  int cur = 0;
  for (int k0=0; k0<EE; k0+=32) {
    if (k0+32 < EE) stage(cur^1, k0+32);
    bf16x8 af[4], bfv[4];
    #pragma unroll
    for (int mi=0;mi<4;++mi) af[mi]  = *(const bf16x8*)&As[cur][wr*64+mi*16+lrow][(lk^pcs)*8];
    #pragma unroll
    for (int ni=0;ni<4;++ni) bfv[ni] = *(const bf16x8*)&Bs[cur][wc*64+ni*16+lrow][(lk^pcs)*8];
    #pragma unroll
    for (int mi=0;mi<4;++mi)
      #pragma unroll
      for (int ni=0;ni<4;++ni)
        acc[mi][ni] = __builtin_amdgcn_mfma_f32_16x16x32_bf16(af[mi], bfv[ni], acc[mi][ni], 0,0,0);
    __syncthreads();
    cur ^= 1;
  }
  const int m_base = bm*128 + wr*64;
  const int n_base = nb*128 + wc*64;
  #pragma unroll
  for (int ni=0;ni<4;++ni) {
    const int col = n_base + ni*16 + lrow;
    const float bias_v = bo[col];
    #pragma unroll
    for (int mi=0;mi<4;++mi) {
      #pragma unroll
      for (int r=0;r<4;++r) {
        int row = m_base + mi*16 + 4*lk + r;
        out[(size_t)row*EE + col] = acc[mi][ni][r] + bias_v;
      }
    }
  }
}

extern "C" void kernel_launch(void* const* d_in, const int* in_sizes, int n_in,
                              void* d_out, int out_size, void* d_ws, size_t ws_size,
                              hipStream_t stream) {
  const float* x    = (const float*)d_in[0];
  const float* ln_w = (const float*)d_in[1];
  const float* ln_b = (const float*)d_in[2];
  const float* wq   = (const float*)d_in[3];
  const float* bq   = (const float*)d_in[4];
  const float* wk   = (const float*)d_in[5];
  const float* bk   = (const float*)d_in[6];
  const float* wv   = (const float*)d_in[7];
  const float* bv   = (const float*)d_in[8];
  const float* wo   = (const float*)d_in[9];
  const float* bo   = (const float*)d_in[10];
  float* out = (float*)d_out;

  char* ws = (char*)d_ws;
  bf16_t* wt  = (bf16_t*)(ws);
  bf16_t* xn  = (bf16_t*)(ws + 4718592);
  bf16_t* qb  = (bf16_t*)(ws + 11010048);
  bf16_t* kb  = (bf16_t*)(ws + 17301504);
  bf16_t* vb  = (bf16_t*)(ws + 23592960);
  bf16_t* vtb = (bf16_t*)(ws + 29884416);
  bf16_t* hb  = (bf16_t*)(ws + 36175872);

  pack_w_kernel  <<<dim3(12,12,4), 256, 0, stream>>>(wq, wk, wv, wo, wt);
  ln_kernel      <<<dim3(NROW),    256, 0, stream>>>(x, ln_w, ln_b, xn);
  gemm_qkv_kernel<<<dim3(32,18),   256, 0, stream>>>(xn, wt, bq, bk, bv, qb, kb, vb);
  vtrans_kernel  <<<dim3(32,24),   256, 0, stream>>>(vb, vtb);
  attn_kernel    <<<dim3(768),     128, 0, stream>>>(qb, kb, vtb, hb);
  gemm_out_kernel<<<dim3(32,6),    256, 0, stream>>>(hb, wt + (size_t)3*EE*EE, bo, out);
}

// Round 11
// 89.608 us; speedup vs baseline: 1.1928x; 1.1928x over previous
//
#include <hip/hip_runtime.h>

typedef __bf16 bf16_t;
typedef __bf16 bf16x8 __attribute__((ext_vector_type(8)));
typedef __bf16 bf16x4 __attribute__((ext_vector_type(4)));
typedef short  s16x4  __attribute__((ext_vector_type(4)));
typedef float  f32x4  __attribute__((ext_vector_type(4)));
typedef unsigned int u32;

#define BB 2
#define SS 2048
#define EE 768
#define HH 12
#define DD 64
#define NROW (BB*SS)   // 4096

// async global->LDS, 16B per lane. LDS dest = firstlane(base)+lane*16 (linear).
#define GLDS16(gp, lp) __builtin_amdgcn_global_load_lds( \
    (const __attribute__((address_space(1))) u32*)(gp),   \
    (__attribute__((address_space(3))) u32*)(lp), 16, 0, 0)

#if __has_builtin(__builtin_amdgcn_mfma_f32_16x16x16bf16_1k)
#define MFMA16_BUILTIN 1
static __device__ __forceinline__ f32x4 mfma_16x16x16_bf16(bf16x4 a, bf16x4 b, f32x4 c) {
  return __builtin_amdgcn_mfma_f32_16x16x16bf16_1k(
      __builtin_bit_cast(s16x4, a), __builtin_bit_cast(s16x4, b), c, 0, 0, 0);
}
#else
#define MFMA16_BUILTIN 0
static __device__ __forceinline__ f32x4 mfma_16x16x16_bf16(bf16x4 a, bf16x4 b, f32x4 c) {
  asm volatile("v_mfma_f32_16x16x16_bf16 %0, %1, %2, %0" : "+v"(c) : "v"(a), "v"(b));
  return c;
}
#endif

// ---------------- pack weights: wt[z][n][k] = w_z[k][n] (bf16) ----------------
__global__ __launch_bounds__(256) void pack_w_kernel(
    const float* __restrict__ wq, const float* __restrict__ wk,
    const float* __restrict__ wv, const float* __restrict__ wo,
    bf16_t* __restrict__ wt)
{
  __shared__ float tile[64][65];
  const float* src = (blockIdx.z==0)?wq:(blockIdx.z==1)?wk:(blockIdx.z==2)?wv:wo;
  const int k0 = blockIdx.x*64, n0 = blockIdx.y*64;
  const int t = threadIdx.x;
  #pragma unroll
  for (int it=0; it<16; ++it) {
    int idx = it*256+t, r = idx>>6, c = idx&63;
    tile[r][c] = src[(size_t)(k0+r)*EE + n0 + c];
  }
  __syncthreads();
  bf16_t* dst = wt + (size_t)blockIdx.z*EE*EE;
  #pragma unroll
  for (int it=0; it<16; ++it) {
    int idx = it*256+t, r = idx>>6, c = idx&63;
    dst[(size_t)(n0+r)*EE + k0 + c] = (bf16_t)tile[c][r];
  }
}

// ---------------- LayerNorm (fp32 in, bf16 out) ----------------
__global__ __launch_bounds__(256) void ln_kernel(
    const float* __restrict__ x, const float* __restrict__ w,
    const float* __restrict__ bvec, bf16_t* __restrict__ xn)
{
  const int row = blockIdx.x, t = threadIdx.x;
  const float* xr = x + (size_t)row*EE;
  float v0 = xr[t], v1 = xr[t+256], v2 = xr[t+512];
  float s  = v0+v1+v2;
  float ss = v0*v0 + v1*v1 + v2*v2;
  #pragma unroll
  for (int m=1; m<64; m<<=1) { s += __shfl_xor(s,m); ss += __shfl_xor(ss,m); }
  __shared__ float red[2][4];
  const int wid = t>>6, lane = t&63;
  if (lane==0) { red[0][wid]=s; red[1][wid]=ss; }
  __syncthreads();
  s  = red[0][0]+red[0][1]+red[0][2]+red[0][3];
  ss = red[1][0]+red[1][1]+red[1][2]+red[1][3];
  const float mu   = s*(1.0f/EE);
  const float rstd = rsqrtf(ss*(1.0f/EE) - mu*mu + 1e-5f);
  bf16_t* xo = xn + (size_t)row*EE;
  xo[t      ] = (bf16_t)((v0-mu)*rstd*w[t      ] + bvec[t      ]);
  xo[t + 256] = (bf16_t)((v1-mu)*rstd*w[t + 256] + bvec[t + 256]);
  xo[t + 512] = (bf16_t)((v2-mu)*rstd*w[t + 512] + bvec[t + 512]);
}

// ---------------- QKV GEMM: BM=128 BN=96 -> 32x24 = 768 blocks (3/CU exact) ----------------
__global__ __launch_bounds__(256) void gemm_qkv_kernel(
    const bf16_t* __restrict__ xn, const bf16_t* __restrict__ wt,
    const float* __restrict__ bq, const float* __restrict__ bk, const float* __restrict__ bv,
    bf16_t* __restrict__ qb, bf16_t* __restrict__ kb, bf16_t* __restrict__ vb)
{
  __shared__ __align__(16) bf16_t As[2][128][32];
  __shared__ __align__(16) bf16_t Bs[2][96][32];
  const int bm = blockIdx.x, by = blockIdx.y;
  const int mat = by >> 3, nb = by & 7;       // 8 panels of 96 per matrix
  const bf16_t* W = wt + (size_t)mat*EE*EE + (size_t)nb*96*EE;
  const float* bias = (mat==0)?bq:(mat==1)?bk:bv;
  bf16_t* outp = (mat==0)?qb:(mat==1)?kb:vb;
  const int t = threadIdx.x, lane = t&63, wid = t>>6;
  const int wr = wid>>1, wc = wid&1;
  const int lrow = lane&15, lk = lane>>4;
  const bf16_t* Ag = xn + (size_t)bm*128*EE;

  const int srow = t>>2, sp = t&3;
  const int sg = sp ^ ((srow>>1)&3);
  const int pcs = (lrow>>1)&3;

  auto stage = [&](int buf, int k0) {
    const bf16_t* asrc = Ag + (size_t)srow*EE + k0 + sg*8;
    const bf16_t* bsrc = W  + (size_t)srow*EE + k0 + sg*8;
    GLDS16(asrc,                 &As[buf][0][0] + t*8);
    GLDS16(asrc + (size_t)64*EE, &As[buf][0][0] + 2048 + t*8);
    GLDS16(bsrc,                 &Bs[buf][0][0] + t*8);
    if (t < 128)   // rows 64..95 of B (wave-uniform guard: waves 0,1)
      GLDS16(bsrc + (size_t)64*EE, &Bs[buf][0][0] + 2048 + t*8);
  };

  f32x4 acc[4][3];
  #pragma unroll
  for (int i=0;i<4;++i)
    #pragma unroll
    for (int j=0;j<3;++j) acc[i][j] = (f32x4){0.f,0.f,0.f,0.f};

  stage(0, 0);
  __syncthreads();
  int cur = 0;
  for (int k0=0; k0<EE; k0+=32) {
    if (k0+32 < EE) stage(cur^1, k0+32);
    bf16x8 af[4], bfv[3];
    #pragma unroll
    for (int mi=0;mi<4;++mi) af[mi]  = *(const bf16x8*)&As[cur][wr*64+mi*16+lrow][(lk^pcs)*8];
    #pragma unroll
    for (int ni=0;ni<3;++ni) bfv[ni] = *(const bf16x8*)&Bs[cur][wc*48+ni*16+lrow][(lk^pcs)*8];
    #pragma unroll
    for (int mi=0;mi<4;++mi)
      #pragma unroll
      for (int ni=0;ni<3;++ni)
        acc[mi][ni] = __builtin_amdgcn_mfma_f32_16x16x32_bf16(af[mi], bfv[ni], acc[mi][ni], 0,0,0);
    __syncthreads();
    cur ^= 1;
  }
  const int m_base = bm*128 + wr*64;
  const int n_base = nb*96 + wc*48;
  #pragma unroll
  for (int ni=0;ni<3;++ni) {
    const int col = n_base + ni*16 + lrow;
    const float bias_v = bias[col];
    #pragma unroll
    for (int mi=0;mi<4;++mi) {
      #pragma unroll
      for (int r=0;r<4;++r) {
        int row = m_base + mi*16 + 4*lk + r;
        outp[(size_t)row*EE + col] = (bf16_t)(acc[mi][ni][r] + bias_v);
      }
    }
  }
}

// ---------------- V transpose: v[b,s,h,d] -> vt[(b*H+h)*D + d][s] ----------------
__global__ __launch_bounds__(256) void vtrans_kernel(
    const bf16_t* __restrict__ v, bf16_t* __restrict__ vt)
{
  __shared__ __align__(16) bf16_t tile[64][72];
  const int j0 = blockIdx.x*64, bh = blockIdx.y;
  const int b = bh/HH, h = bh%HH;
  const int t = threadIdx.x;
  #pragma unroll
  for (int it=0; it<2; ++it) {
    int idx = it*256+t, r = idx>>3, c8 = (idx&7)*8;
    *(bf16x8*)&tile[r][c8] = *(const bf16x8*)(v + (size_t)(b*SS + j0 + r)*EE + h*DD + c8);
  }
  __syncthreads();
  #pragma unroll
  for (int it=0; it<2; ++it) {
    int idx = it*256+t, d = idx>>3, c8 = (idx&7)*8;
    bf16x8 val;
    #pragma unroll
    for (int i=0;i<8;++i) val[i] = tile[c8+i][d];
    *(bf16x8*)(vt + ((size_t)bh*DD + d)*SS + j0 + c8) = val;
  }
}

// ---------------- flash attention (anti-causal: attend j >= i) ----------------
// Q-RESIDENT J-SPLIT: 4 waves, 64 q-rows/block. Each wave holds FOUR q-groups'
// Q fragments in registers (loop-invariant) and owns a 16-j SLICE of every
// staged 64-j tile. Each K/V LDS fragment is read ONCE and feeds 4 q-groups'
// MFMAs -> 4x less LDS traffic per q-row than R4 at IDENTICAL occupancy
// (768-block snake, 12 waves/CU), staging, and verified fragment layouts.
// Fixed-max softmax (additive) -> per-wave j-partials merged once at the end
// through a f32 LDS buffer (4 serialized add phases).
__global__ __launch_bounds__(256, 3) void attn_kernel(
    const bf16_t* __restrict__ qb, const bf16_t* __restrict__ kb,
    const bf16_t* __restrict__ vt, bf16_t* __restrict__ hb)
{
  __shared__ __align__(16) bf16_t Ks[2][64][64];   // K tile [j][d]
  __shared__ __align__(16) bf16_t Vts[2][64][64];  // V^T tile [d][j]
  __shared__ __align__(16) float  Osum[64][68];    // O merge [q][d] (+pad)
  __shared__ float Lsum[4][64];                    // lsum partial [wave][q]

  // snake remap: blocks bid, bid+256, bid+512 share a CU -> complementary work
  const int bid = blockIdx.x;
  const int rnd = bid >> 8, g8 = bid & 255;
  const int item = (rnd == 1) ? (511 - g8) : (rnd*256 + g8);
  const int qt = item / 24, bh = item % 24;

  const int i0 = qt*64, b = bh/HH, h = bh%HH;
  const int t = threadIdx.x, lane = t&63, w = t>>6;   // w = wave id = j-slice
  const int lrow = lane&15, lk = lane>>4;

  const int sr = t>>3, sp = t&7;
  const int sgc = sp ^ (sr&7);
  const bf16_t* kbase  = kb + (size_t)b*SS*EE + h*DD;
  const bf16_t* vtbase = vt + (size_t)bh*DD*SS;

  // Q fragments (B-operand), 4 groups of 16 q-rows — loop-invariant registers
  bf16x8 qf[4][2];
  #pragma unroll
  for (int g=0; g<4; ++g) {
    const bf16_t* qrow = qb + (size_t)(b*SS + i0 + g*16 + lrow)*EE + h*DD;
    qf[g][0] = *(const bf16x8*)(qrow + lk*8);
    qf[g][1] = *(const bf16x8*)(qrow + 32 + lk*8);
  }

  // acc[g][sd][r] = O[d = sd*16+4lk+r][q = g*16+lrow], partial over wave's j-slices
  f32x4 acc[4][4];
  #pragma unroll
  for (int g=0; g<4; ++g)
    #pragma unroll
    for (int i=0;i<4;++i) acc[g][i] = (f32x4){0.f,0.f,0.f,0.f};
  float lsum[4] = {0.f,0.f,0.f,0.f};
  const int kkey = lrow&7;

  auto stage = [&](int buf, int jt) {
    const int j0v = jt*64;
    const bf16_t* ksrc = kbase  + (size_t)(j0v + sr)*EE + sgc*8;
    const bf16_t* vsrc = vtbase + (size_t)sr*SS + j0v + sgc*8;
    GLDS16(ksrc,                 &Ks[buf][0][0]  + t*8);
    GLDS16(ksrc + (size_t)32*EE, &Ks[buf][0][0]  + 2048 + t*8);
    GLDS16(vsrc,                 &Vts[buf][0][0] + t*8);
    GLDS16(vsrc + (size_t)32*SS, &Vts[buf][0][0] + 2048 + t*8);
  };

  // Per tile, this wave covers j-local = w*16 + 4*lk + r (its 16-j slice).
  // p = e^(qk/8 - 24) = 2^(a*0.1803369 - 34.62468); fixed max -> additive
#define ATTN_TILE(CUR, MASKED) do {                                          \
    const bf16_t* krow = &Ks[CUR][w*16 + lrow][0];                           \
    bf16x8 kf0 = *(const bf16x8*)(krow + ((lk^kkey)<<3));                    \
    bf16x8 kf1 = *(const bf16x8*)(krow + (((lk+4)^kkey)<<3));                \
    bf16x4 pb[4];                                                            \
    _Pragma("unroll")                                                        \
    for (int g=0; g<4; ++g) {                                                \
      f32x4 a = (f32x4){0.f,0.f,0.f,0.f};                                    \
      a = __builtin_amdgcn_mfma_f32_16x16x32_bf16(kf0, qf[g][0], a, 0,0,0);  \
      a = __builtin_amdgcn_mfma_f32_16x16x32_bf16(kf1, qf[g][1], a, 0,0,0);  \
      _Pragma("unroll")                                                      \
      for (int r=0;r<4;++r) {                                                \
        float ee = a[r]*0.180336878f - 34.6246784f;                          \
        if (MASKED && (w*16 + 4*lk + r) < (g*16 + lrow)) ee = -1e30f;        \
        float p = exp2f(ee);                                                 \
        lsum[g] += p;                                                        \
        pb[g][r] = (bf16_t)p;                                                \
      }                                                                      \
    }                                                                        \
    _Pragma("unroll")                                                        \
    for (int sd=0;sd<4;++sd) {                                               \
      const bf16_t* vrow = &Vts[CUR][sd*16+lrow][0];                         \
      bf16x4 vf = *(const bf16x4*)(vrow + (((2*w+(lk>>1))^kkey)<<3) + ((lk&1)<<2)); \
      _Pragma("unroll")                                                      \
      for (int g=0; g<4; ++g)                                                \
        acc[g][sd] = mfma_16x16x16_bf16(vf, pb[g], acc[g][sd]);              \
    }                                                                        \
  } while(0)

  const int ntiles = SS/64 - qt;  // 1..32
  stage(0, qt);
  __syncthreads();                 // buf0 ready
  if (ntiles > 1) stage(1, qt+1);  // prefetch flies under diagonal compute
  ATTN_TILE(0, true);              // diagonal tile, masked
#if !MFMA16_BUILTIN
  asm volatile("s_nop 7\n\ts_nop 7");
#endif
  __syncthreads();

  int cur = 1;
  for (int it2=1; it2<ntiles; ++it2) {
    if (it2+1 < ntiles) stage(cur^1, qt+it2+1);
    ATTN_TILE(cur, false);
#if !MFMA16_BUILTIN
    asm volatile("s_nop 7\n\ts_nop 7");
#endif
    __syncthreads();
    cur ^= 1;
  }
#undef ATTN_TILE

  // lsum: reduce across lk (j within slice); store per-wave partials
  #pragma unroll
  for (int g=0; g<4; ++g) {
    lsum[g] += __shfl_xor(lsum[g], 16);
    lsum[g] += __shfl_xor(lsum[g], 32);
  }
  if (lane < 16) {
    #pragma unroll
    for (int g=0; g<4; ++g) Lsum[w][g*16 + lane] = lsum[g];
  }

  // O merge across waves (each holds a j-partial of the FULL 64q x 64d tile)
  __syncthreads();
  if (w == 0) {
    #pragma unroll
    for (int g=0; g<4; ++g)
      #pragma unroll
      for (int sd=0; sd<4; ++sd)
        *(f32x4*)&Osum[g*16+lrow][sd*16 + 4*lk] = acc[g][sd];
  }
  __syncthreads();
  if (w == 1) {
    #pragma unroll
    for (int g=0; g<4; ++g)
      #pragma unroll
      for (int sd=0; sd<4; ++sd) {
        f32x4 v = *(f32x4*)&Osum[g*16+lrow][sd*16 + 4*lk];
        *(f32x4*)&Osum[g*16+lrow][sd*16 + 4*lk] = v + acc[g][sd];
      }
  }
  __syncthreads();
  if (w == 2) {
    #pragma unroll
    for (int g=0; g<4; ++g)
      #pragma unroll
      for (int sd=0; sd<4; ++sd) {
        f32x4 v = *(f32x4*)&Osum[g*16+lrow][sd*16 + 4*lk];
        *(f32x4*)&Osum[g*16+lrow][sd*16 + 4*lk] = v + acc[g][sd];
      }
  }
  __syncthreads();
  if (w == 3) {
    #pragma unroll
    for (int g=0; g<4; ++g)
      #pragma unroll
      for (int sd=0; sd<4; ++sd) {
        f32x4 v = *(f32x4*)&Osum[g*16+lrow][sd*16 + 4*lk];
        *(f32x4*)&Osum[g*16+lrow][sd*16 + 4*lk] = v + acc[g][sd];
      }
  }
  __syncthreads();

  // final: normalize + coalesced bf16 store (thread t: q = t>>2, 16 d each)
  const int q = t>>2, dq = t&3;
  const float ltot = Lsum[0][q] + Lsum[1][q] + Lsum[2][q] + Lsum[3][q];
  const float inv = 1.0f / ltot;
  bf16_t* orow = hb + (size_t)(b*SS + i0 + q)*EE + h*DD + dq*16;
  bf16x8 o0, o1;
  #pragma unroll
  for (int c=0;c<2;++c) {
    f32x4 v0 = *(const f32x4*)&Osum[q][dq*16 + c*8];
    f32x4 v1 = *(const f32x4*)&Osum[q][dq*16 + c*8 + 4];
    #pragma unroll
    for (int i=0;i<4;++i) {
      if (c==0) { o0[i] = (bf16_t)(v0[i]*inv); o0[i+4] = (bf16_t)(v1[i]*inv); }
      else      { o1[i] = (bf16_t)(v0[i]*inv); o1[i+4] = (bf16_t)(v1[i]*inv); }
    }
  }
  *(bf16x8*)orow = o0;
  *(bf16x8*)(orow+8) = o1;
}

// ---------------- output GEMM: BM=64 BN=96 -> 64x8 = 512 blocks (2/CU) ----------------
__global__ __launch_bounds__(256) void gemm_out_kernel(
    const bf16_t* __restrict__ hbuf, const bf16_t* __restrict__ wto,
    const float* __restrict__ bo, float* __restrict__ out)
{
  __shared__ __align__(16) bf16_t As[2][64][32];
  __shared__ __align__(16) bf16_t Bs[2][96][32];
  const int bm = blockIdx.x, nb = blockIdx.y;
  const bf16_t* W = wto + (size_t)nb*96*EE;
  const int t = threadIdx.x, lane = t&63, wid = t>>6;
  const int wr = wid>>1, wc = wid&1;
  const int lrow = lane&15, lk = lane>>4;
  const bf16_t* Ag = hbuf + (size_t)bm*64*EE;

  const int srow = t>>2, sp = t&3;
  const int sg = sp ^ ((srow>>1)&3);
  const int pcs = (lrow>>1)&3;

  auto stage = [&](int buf, int k0) {
    const bf16_t* asrc = Ag + (size_t)srow*EE + k0 + sg*8;
    const bf16_t* bsrc = W  + (size_t)srow*EE + k0 + sg*8;
    GLDS16(asrc, &As[buf][0][0] + t*8);
    GLDS16(bsrc, &Bs[buf][0][0] + t*8);
    if (t < 128)
      GLDS16(bsrc + (size_t)64*EE, &Bs[buf][0][0] + 2048 + t*8);
  };

  f32x4 acc[2][3];
  #pragma unroll
  for (int i=0;i<2;++i)
    #pragma unroll
    for (int j=0;j<3;++j) acc[i][j] = (f32x4){0.f,0.f,0.f,0.f};

  stage(0, 0);
  __syncthreads();
  int cur = 0;
  for (int k0=0; k0<EE; k0+=32) {
    if (k0+32 < EE) stage(cur^1, k0+32);
    bf16x8 af[2], bfv[3];
    #pragma unroll
    for (int mi=0;mi<2;++mi) af[mi]  = *(const bf16x8*)&As[cur][wr*32+mi*16+lrow][(lk^pcs)*8];
    #pragma unroll
    for (int ni=0;ni<3;++ni) bfv[ni] = *(const bf16x8*)&Bs[cur][wc*48+ni*16+lrow][(lk^pcs)*8];
    #pragma unroll
    for (int mi=0;mi<2;++mi)
      #pragma unroll
      for (int ni=0;ni<3;++ni)
        acc[mi][ni] = __builtin_amdgcn_mfma_f32_16x16x32_bf16(af[mi], bfv[ni], acc[mi][ni], 0,0,0);
    __syncthreads();
    cur ^= 1;
  }
  const int m_base = bm*64 + wr*32;
  const int n_base = nb*96 + wc*48;
  #pragma unroll
  for (int ni=0;ni<3;++ni) {
    const int col = n_base + ni*16 + lrow;
    const float bias_v = bo[col];
    #pragma unroll
    for (int mi=0;mi<2;++mi) {
      #pragma unroll
      for (int r=0;r<4;++r) {
        int row = m_base + mi*16 + 4*lk + r;
        out[(size_t)row*EE + col] = acc[mi][ni][r] + bias_v;
      }
    }
  }
}

extern "C" void kernel_launch(void* const* d_in, const int* in_sizes, int n_in,
                              void* d_out, int out_size, void* d_ws, size_t ws_size,
                              hipStream_t stream) {
  const float* x    = (const float*)d_in[0];
  const float* ln_w = (const float*)d_in[1];
  const float* ln_b = (const float*)d_in[2];
  const float* wq   = (const float*)d_in[3];
  const float* bq   = (const float*)d_in[4];
  const float* wk   = (const float*)d_in[5];
  const float* bk   = (const float*)d_in[6];
  const float* wv   = (const float*)d_in[7];
  const float* bv   = (const float*)d_in[8];
  const float* wo   = (const float*)d_in[9];
  const float* bo   = (const float*)d_in[10];
  float* out = (float*)d_out;

  char* ws = (char*)d_ws;
  bf16_t* wt  = (bf16_t*)(ws);
  bf16_t* xn  = (bf16_t*)(ws + 4718592);
  bf16_t* qb  = (bf16_t*)(ws + 11010048);
  bf16_t* kb  = (bf16_t*)(ws + 17301504);
  bf16_t* vb  = (bf16_t*)(ws + 23592960);
  bf16_t* vtb = (bf16_t*)(ws + 29884416);
  bf16_t* hb  = (bf16_t*)(ws + 36175872);

  pack_w_kernel  <<<dim3(12,12,4), 256, 0, stream>>>(wq, wk, wv, wo, wt);
  ln_kernel      <<<dim3(NROW),    256, 0, stream>>>(x, ln_w, ln_b, xn);
  gemm_qkv_kernel<<<dim3(32,24),   256, 0, stream>>>(xn, wt, bq, bk, bv, qb, kb, vb);
  vtrans_kernel  <<<dim3(32,24),   256, 0, stream>>>(vb, vtb);
  attn_kernel    <<<dim3(768),     256, 0, stream>>>(qb, kb, vtb, hb);
  gemm_out_kernel<<<dim3(64,8),    256, 0, stream>>>(hb, wt + (size_t)3*EE*EE, bo, out);
}